// Round 1
// baseline (6389.895 us; speedup 1.0000x reference)
//
#include <hip/hip_runtime.h>
#include <math.h>
#include <cstddef>

// Problem constants (match reference setup_inputs):
//   B=2, S=2048, H=1024, NUM_HEADS=16, hd=64, MAX_REL=128 -> 257 table rows
// Workspace layout (floats), total ~134.5 MB:
//   Qw  [32][2048][64]   4,194,304
//   Kw  [32][2048][64]   4,194,304
//   Vw  [32][2048][64]   4,194,304
//   relP[32][2048][257] 16,842,752   (relP[bh][q][r] = q-row . Tk[r])
//   Ow  [4096][1024]     4,194,304   (attention output, [B,S,H] row-major)

#define S_ 2048
#define H_ 1024
#define NREL 257

// ---------------------------------------------------------------------------
// GEMM: Y = X[4096,1024] @ W[1024,1024] + bias
// MODE 0: scatter output to head layout [B,16,S,64]; MODE 1: flat [4096,1024]
// 64x64 tile, 256 threads (16x16), 4x4 micro-tile, K-step 32.
// ---------------------------------------------------------------------------
template<int MODE>
__global__ __launch_bounds__(256) void proj_gemm(const float* __restrict__ X,
        const float* __restrict__ W, const float* __restrict__ bias,
        float* __restrict__ Y) {
    const int K = H_, N = H_;
    __shared__ float As[32][68];   // [kk][m] (transposed A tile)
    __shared__ float Bs[32][64];   // [kk][n]
    const int m0 = blockIdx.y * 64;
    const int n0 = blockIdx.x * 64;
    const int t = threadIdx.x;
    const int tx = t & 15, ty = t >> 4;
    float acc[4][4] = {};
    for (int k0 = 0; k0 < K; k0 += 32) {
        __syncthreads();
        #pragma unroll
        for (int j = 0; j < 2; ++j) {           // A tile 64x32
            int f = t + j * 256;
            int row = f >> 3, cb = f & 7;
            float4 a4 = *reinterpret_cast<const float4*>(
                &X[(size_t)(m0 + row) * K + k0 + cb * 4]);
            As[cb*4+0][row] = a4.x; As[cb*4+1][row] = a4.y;
            As[cb*4+2][row] = a4.z; As[cb*4+3][row] = a4.w;
        }
        #pragma unroll
        for (int j = 0; j < 2; ++j) {           // B tile 32x64
            int f = t + j * 256;
            int kk = f >> 4, nb = f & 15;
            *reinterpret_cast<float4*>(&Bs[kk][nb*4]) =
                *reinterpret_cast<const float4*>(&W[(size_t)(k0 + kk) * N + n0 + nb * 4]);
        }
        __syncthreads();
        #pragma unroll
        for (int kk = 0; kk < 32; ++kk) {
            float a[4], b[4];
            *reinterpret_cast<float4*>(a) = *reinterpret_cast<float4*>(&As[kk][ty*4]);
            *reinterpret_cast<float4*>(b) = *reinterpret_cast<float4*>(&Bs[kk][tx*4]);
            #pragma unroll
            for (int i = 0; i < 4; ++i)
                #pragma unroll
                for (int j = 0; j < 4; ++j)
                    acc[i][j] += a[i] * b[j];
        }
    }
    const float4 b4 = *reinterpret_cast<const float4*>(&bias[n0 + tx*4]);
    const float bb[4] = {b4.x, b4.y, b4.z, b4.w};
    #pragma unroll
    for (int i = 0; i < 4; ++i) {
        const int row = m0 + ty*4 + i;
        float4 res;
        res.x = acc[i][0] + bb[0]; res.y = acc[i][1] + bb[1];
        res.z = acc[i][2] + bb[2]; res.w = acc[i][3] + bb[3];
        if (MODE == 0) {
            const int b = row >> 11, s = row & 2047;
            const int h = blockIdx.x;            // n0/64; heads are 64-col aligned
            *reinterpret_cast<float4*>(
                &Y[(((size_t)b*16 + h)*S_ + s)*64 + tx*4]) = res;
        } else {
            *reinterpret_cast<float4*>(&Y[(size_t)row * N + n0 + tx*4]) = res;
        }
    }
}

// ---------------------------------------------------------------------------
// relP[bh][s][i] = sum_d Qw[bh][s][d] * Tk[i][d],  i in [0,257)
// 64(s) x 64(i) tile, K-dim = d = 64. Grid: (5 i-tiles, 32 s-tiles, 32 bh)
// ---------------------------------------------------------------------------
__global__ __launch_bounds__(256) void relp_gemm(const float* __restrict__ Qw,
        const float* __restrict__ Tk, float* __restrict__ relPg) {
    __shared__ float As[64][68];   // [d][srow]
    __shared__ float Bs[64][68];   // [d][i]
    const int bh = blockIdx.z;
    const int s0 = blockIdx.y * 64;
    const int i0 = blockIdx.x * 64;
    const int t = threadIdx.x;
    const int tx = t & 15, ty = t >> 4;
    #pragma unroll
    for (int j = 0; j < 4; ++j) {
        int f = t + j * 256;
        int row = f >> 4, db = f & 15;
        float4 q4 = *reinterpret_cast<const float4*>(
            &Qw[((size_t)bh * S_ + s0 + row) * 64 + db * 4]);
        As[db*4+0][row] = q4.x; As[db*4+1][row] = q4.y;
        As[db*4+2][row] = q4.z; As[db*4+3][row] = q4.w;
        int i = i0 + row;
        float4 t4 = make_float4(0.f, 0.f, 0.f, 0.f);
        if (i < NREL)
            t4 = *reinterpret_cast<const float4*>(&Tk[(size_t)i * 64 + db * 4]);
        Bs[db*4+0][row] = t4.x; Bs[db*4+1][row] = t4.y;
        Bs[db*4+2][row] = t4.z; Bs[db*4+3][row] = t4.w;
    }
    __syncthreads();
    float acc[4][4] = {};
    #pragma unroll
    for (int d = 0; d < 64; ++d) {
        float a[4], b[4];
        *reinterpret_cast<float4*>(a) = *reinterpret_cast<float4*>(&As[d][ty*4]);
        *reinterpret_cast<float4*>(b) = *reinterpret_cast<float4*>(&Bs[d][tx*4]);
        #pragma unroll
        for (int i = 0; i < 4; ++i)
            #pragma unroll
            for (int j = 0; j < 4; ++j)
                acc[i][j] += a[i] * b[j];
    }
    #pragma unroll
    for (int i = 0; i < 4; ++i) {
        const int srow = s0 + ty*4 + i;
        #pragma unroll
        for (int j = 0; j < 4; ++j) {
            const int ic = i0 + tx*4 + j;
            if (ic < NREL)
                relPg[((size_t)bh * S_ + srow) * NREL + ic] = acc[i][j];
        }
    }
}

// ---------------------------------------------------------------------------
// Flash attention with relative position encoding.
// Block = 256 threads = 4 waves; wave w owns q-rows r0 + w*4 .. w*4+3.
// K-tile = 64. LDS 56 KB -> 2 blocks/CU.
//   scores s = (q.k + relP[q, id(q,k)]) / 8, online softmax.
//   rel_v: tails (id 0/256) as rescaled sums; middle ids (1..255) store the
//   RAW score in wmid (unique k per id) -> epilogue: exp(w - m)/l * Tv[id].
// ---------------------------------------------------------------------------
__global__ __launch_bounds__(256) void flash_attn(const float* __restrict__ Qw,
        const float* __restrict__ Kw, const float* __restrict__ Vw,
        const float* __restrict__ relPg, const float* __restrict__ Tv,
        float* __restrict__ Ow) {
    __shared__ float Ks[64][64];       // [k'][ (db ^ (k'&7))*4 + e ]  swizzled
    __shared__ float Vt[64][64];       // [d ][ ((k>>2)^(d&7))*4 + (k&3) ]
    __shared__ float q_lds[16][64];
    __shared__ float wmid[16][256];    // raw scaled scores for ids 1..255
    __shared__ float p_lds[4][4][64];

    const int t = threadIdx.x;
    const int w = t >> 6, lane = t & 63;
    const int bh = blockIdx.y;
    const int r0 = blockIdx.x * 16;
    const size_t bhS = (size_t)bh * S_;

    #pragma unroll
    for (int j = 0; j < 4; ++j) {
        int row = j * 4 + w;
        q_lds[row][lane] = Qw[(bhS + r0 + row) * 64 + lane];
    }
    for (int idx = t; idx < 16 * 256; idx += 256)
        wmid[idx >> 8][idx & 255] = -INFINITY;

    float m_r[4], l_r[4], wL[4], wR[4], oacc[4];
    #pragma unroll
    for (int i = 0; i < 4; ++i) {
        m_r[i] = -INFINITY; l_r[i] = 0.f; wL[i] = 0.f; wR[i] = 0.f; oacc[i] = 0.f;
    }

    for (int k0 = 0; k0 < S_; k0 += 64) {
        __syncthreads();
        #pragma unroll
        for (int j = 0; j < 4; ++j) {           // stage K,V tiles (64x64 each)
            int f = t + j * 256;
            int kr = f >> 4, db = f & 15;
            size_t g = (bhS + k0 + kr) * 64 + db * 4;
            float4 kv = *reinterpret_cast<const float4*>(&Kw[g]);
            *reinterpret_cast<float4*>(&Ks[kr][(db ^ (kr & 7)) * 4]) = kv;
            float4 vv = *reinterpret_cast<const float4*>(&Vw[g]);
            const float ve[4] = {vv.x, vv.y, vv.z, vv.w};
            #pragma unroll
            for (int i2 = 0; i2 < 4; ++i2) {
                int d = db * 4 + i2;
                Vt[d][((kr >> 2) ^ (d & 7)) * 4 + (kr & 3)] = ve[i2];
            }
        }
        __syncthreads();

        // QK^T: lane computes score for k = k0 + lane, for its wave's 4 rows
        float sc[4] = {0.f, 0.f, 0.f, 0.f};
        #pragma unroll
        for (int dblk = 0; dblk < 16; ++dblk) {
            float4 kv = *reinterpret_cast<float4*>(&Ks[lane][(dblk ^ (lane & 7)) * 4]);
            #pragma unroll
            for (int rI = 0; rI < 4; ++rI) {
                float4 qv = *reinterpret_cast<float4*>(&q_lds[w*4 + rI][dblk*4]);
                sc[rI] += kv.x*qv.x + kv.y*qv.y + kv.z*qv.z + kv.w*qv.w;
            }
        }

        const int kglob = k0 + lane;
        #pragma unroll
        for (int rI = 0; rI < 4; ++rI) {
            const int row = w*4 + rI;
            const int r = r0 + row;
            int rel = r - kglob;
            rel = rel > 128 ? 128 : (rel < -128 ? -128 : rel);
            const int id = rel + 128;
            const float s = (sc[rI] + relPg[(bhS + r) * NREL + id]) * 0.125f;
            float tm = s;
            #pragma unroll
            for (int off = 32; off; off >>= 1) tm = fmaxf(tm, __shfl_xor(tm, off));
            const float newm = fmaxf(m_r[rI], tm);
            const float resc = __expf(m_r[rI] - newm);
            const float p = __expf(s - newm);
            float ts = p;
            float tl = (id == 256) ? p : 0.f;
            float tr = (id == 0)   ? p : 0.f;
            #pragma unroll
            for (int off = 32; off; off >>= 1) {
                ts += __shfl_xor(ts, off);
                tl += __shfl_xor(tl, off);
                tr += __shfl_xor(tr, off);
            }
            l_r[rI] = l_r[rI] * resc + ts;
            wL[rI]  = wL[rI]  * resc + tl;
            wR[rI]  = wR[rI]  * resc + tr;
            m_r[rI] = newm;
            oacc[rI] *= resc;
            if (id > 0 && id < 256) wmid[row][id] = s;   // unique k per id
            p_lds[w][rI][lane] = p;
        }

        // PV: lane = output dim d; accumulate over the 64 k of this tile
        #pragma unroll
        for (int kb = 0; kb < 16; ++kb) {
            float4 vv = *reinterpret_cast<float4*>(&Vt[lane][(kb ^ (lane & 7)) * 4]);
            #pragma unroll
            for (int rI = 0; rI < 4; ++rI) {
                float4 pv = *reinterpret_cast<float4*>(&p_lds[w][rI][kb*4]);
                oacc[rI] += vv.x*pv.x + vv.y*pv.y + vv.z*pv.z + vv.w*pv.w;
            }
        }
    }

    // Epilogue: rel_v contribution + normalize + store [B,S,H]
    const int b = bh >> 4, h = bh & 15;
    #pragma unroll
    for (int rI = 0; rI < 4; ++rI) {
        const int row = w*4 + rI;
        const int r = r0 + row;
        const float m = m_r[rI];
        float o = oacc[rI] + wL[rI] * Tv[256*64 + lane] + wR[rI] * Tv[lane];
        for (int id = 1; id < 256; ++id) {
            const float wv = wmid[row][id];        // LDS broadcast, uniform branch
            if (wv > -1e30f)
                o += __expf(wv - m) * Tv[(size_t)id * 64 + lane];
        }
        Ow[((size_t)(b * S_ + r)) * H_ + h * 64 + lane] = o / l_r[rI];
    }
}

// ---------------------------------------------------------------------------
extern "C" void kernel_launch(void* const* d_in, const int* in_sizes, int n_in,
                              void* d_out, int out_size, void* d_ws, size_t ws_size,
                              hipStream_t stream) {
    const float* query = (const float*)d_in[0];
    const float* key_  = (const float*)d_in[1];
    const float* value = (const float*)d_in[2];
    const float* Wq = (const float*)d_in[3];
    const float* bq = (const float*)d_in[4];
    const float* Wk = (const float*)d_in[5];
    const float* bk = (const float*)d_in[6];
    const float* Wv = (const float*)d_in[7];
    const float* bv = (const float*)d_in[8];
    const float* Wo = (const float*)d_in[9];
    const float* bo = (const float*)d_in[10];
    const float* Tk = (const float*)d_in[11];
    const float* Tv = (const float*)d_in[12];

    float* ws = (float*)d_ws;
    const size_t QKV = (size_t)32 * S_ * 64;          // 4,194,304 floats
    float* Qw    = ws;
    float* Kw    = Qw + QKV;
    float* Vw    = Kw + QKV;
    float* relPg = Vw + QKV;
    float* Ow    = relPg + (size_t)32 * S_ * NREL;    // 16,842,752 floats

    const dim3 gemmGrid(16, 64), blk(256);
    proj_gemm<0><<<gemmGrid, blk, 0, stream>>>(query, Wq, bq, Qw);
    proj_gemm<0><<<gemmGrid, blk, 0, stream>>>(key_,  Wk, bk, Kw);
    proj_gemm<0><<<gemmGrid, blk, 0, stream>>>(value, Wv, bv, Vw);
    relp_gemm<<<dim3(5, 32, 32), blk, 0, stream>>>(Qw, Tk, relPg);
    flash_attn<<<dim3(S_ / 16, 32), blk, 0, stream>>>(Qw, Kw, Vw, relPg, Tv, Ow);
    proj_gemm<1><<<gemmGrid, blk, 0, stream>>>(Ow, Wo, bo, (float*)d_out);
}

// Round 3
// 1233.614 us; speedup vs baseline: 5.1798x; 5.1798x over previous
//
#include <hip/hip_runtime.h>
#include <math.h>
#include <cstddef>

// B=2, S=2048, H=1024, NUM_HEADS=16, hd=64, MAX_REL=128 -> 257 table rows
// Workspace (floats), ~134.7 MB total:
//   Qw   [32][2048][64]    4,194,304   (Q head layout)
//   KwT  [32][64][2048]    4,194,304   (K head layout, TRANSPOSED d-major)
//   Vw   [32][2048][64]    4,194,304
//   relP [32][2048][257]  16,842,752   (bias table; overwritten in-place with
//                                       unnormalized attn-by-id weights "AW")
//   Ow   [2][2048][1024]   4,194,304   (attention output, [B,S,H])
//   Lrow [32][2048]           65,536   (softmax denominators)

#define S_ 2048
#define H_ 1024
#define NREL 257

// ---------------------------------------------------------------------------
// GEMM: Y = X[4096,1024] @ W[1024,1024] + bias
// MODE 0: head layout [B,16,S,64]; MODE 1: flat [4096,1024];
// MODE 2: head layout TRANSPOSED [B*16][64 d][2048 s]  (for K)
// ---------------------------------------------------------------------------
template<int MODE>
__global__ __launch_bounds__(256) void proj_gemm(const float* __restrict__ X,
        const float* __restrict__ W, const float* __restrict__ bias,
        float* __restrict__ Y) {
    const int K = H_, N = H_;
    __shared__ float As[32][68];   // [kk][m] (transposed A tile)
    __shared__ float Bs[32][64];   // [kk][n]
    const int m0 = blockIdx.y * 64;
    const int n0 = blockIdx.x * 64;
    const int t = threadIdx.x;
    const int tx = t & 15, ty = t >> 4;
    float acc[4][4] = {};
    for (int k0 = 0; k0 < K; k0 += 32) {
        __syncthreads();
        #pragma unroll
        for (int j = 0; j < 2; ++j) {           // A tile 64x32
            int f = t + j * 256;
            int row = f >> 3, cb = f & 7;
            float4 a4 = *reinterpret_cast<const float4*>(
                &X[(size_t)(m0 + row) * K + k0 + cb * 4]);
            As[cb*4+0][row] = a4.x; As[cb*4+1][row] = a4.y;
            As[cb*4+2][row] = a4.z; As[cb*4+3][row] = a4.w;
        }
        #pragma unroll
        for (int j = 0; j < 2; ++j) {           // B tile 32x64
            int f = t + j * 256;
            int kk = f >> 4, nb = f & 15;
            *reinterpret_cast<float4*>(&Bs[kk][nb*4]) =
                *reinterpret_cast<const float4*>(&W[(size_t)(k0 + kk) * N + n0 + nb * 4]);
        }
        __syncthreads();
        #pragma unroll
        for (int kk = 0; kk < 32; ++kk) {
            float a[4], b[4];
            *reinterpret_cast<float4*>(a) = *reinterpret_cast<float4*>(&As[kk][ty*4]);
            *reinterpret_cast<float4*>(b) = *reinterpret_cast<float4*>(&Bs[kk][tx*4]);
            #pragma unroll
            for (int i = 0; i < 4; ++i)
                #pragma unroll
                for (int j = 0; j < 4; ++j)
                    acc[i][j] += a[i] * b[j];
        }
    }
    const float4 b4 = *reinterpret_cast<const float4*>(&bias[n0 + tx*4]);
    const float bb[4] = {b4.x, b4.y, b4.z, b4.w};
    #pragma unroll
    for (int i = 0; i < 4; ++i) {
        const int row = m0 + ty*4 + i;
        float res[4];
        #pragma unroll
        for (int j = 0; j < 4; ++j) res[j] = acc[i][j] + bb[j];
        if (MODE == 0) {
            const int b = row >> 11, s = row & 2047;
            const int h = blockIdx.x;            // heads are 64-col aligned
            *reinterpret_cast<float4*>(
                &Y[(((size_t)b*16 + h)*S_ + s)*64 + tx*4]) =
                make_float4(res[0], res[1], res[2], res[3]);
        } else if (MODE == 1) {
            *reinterpret_cast<float4*>(&Y[(size_t)row * N + n0 + tx*4]) =
                make_float4(res[0], res[1], res[2], res[3]);
        } else {
            const int b = row >> 11, s = row & 2047;
            const int h = blockIdx.x;
            const size_t base = ((size_t)b*16 + h) * 64;
            #pragma unroll
            for (int j = 0; j < 4; ++j)
                Y[(base + tx*4 + j) * S_ + s] = res[j];   // d-major scatter
        }
    }
}

// ---------------------------------------------------------------------------
// relP[bh][s][i] = sum_d Qw[bh][s][d] * Tk[i][d],  i in [0,257)
// ---------------------------------------------------------------------------
__global__ __launch_bounds__(256) void relp_gemm(const float* __restrict__ Qw,
        const float* __restrict__ Tk, float* __restrict__ relPg) {
    __shared__ float As[64][68];   // [d][srow]
    __shared__ float Bs[64][68];   // [d][i]
    const int bh = blockIdx.z;
    const int s0 = blockIdx.y * 64;
    const int i0 = blockIdx.x * 64;
    const int t = threadIdx.x;
    const int tx = t & 15, ty = t >> 4;
    #pragma unroll
    for (int j = 0; j < 4; ++j) {
        int f = t + j * 256;
        int row = f >> 4, db = f & 15;
        float4 q4 = *reinterpret_cast<const float4*>(
            &Qw[((size_t)bh * S_ + s0 + row) * 64 + db * 4]);
        As[db*4+0][row] = q4.x; As[db*4+1][row] = q4.y;
        As[db*4+2][row] = q4.z; As[db*4+3][row] = q4.w;
        int i = i0 + row;
        float4 t4 = make_float4(0.f, 0.f, 0.f, 0.f);
        if (i < NREL)
            t4 = *reinterpret_cast<const float4*>(&Tk[(size_t)i * 64 + db * 4]);
        Bs[db*4+0][row] = t4.x; Bs[db*4+1][row] = t4.y;
        Bs[db*4+2][row] = t4.z; Bs[db*4+3][row] = t4.w;
    }
    __syncthreads();
    float acc[4][4] = {};
    #pragma unroll 8
    for (int d = 0; d < 64; ++d) {
        float a[4], b[4];
        *reinterpret_cast<float4*>(a) = *reinterpret_cast<float4*>(&As[d][ty*4]);
        *reinterpret_cast<float4*>(b) = *reinterpret_cast<float4*>(&Bs[d][tx*4]);
        #pragma unroll
        for (int i = 0; i < 4; ++i)
            #pragma unroll
            for (int j = 0; j < 4; ++j)
                acc[i][j] += a[i] * b[j];
    }
    #pragma unroll
    for (int i = 0; i < 4; ++i) {
        const int srow = s0 + ty*4 + i;
        #pragma unroll
        for (int j = 0; j < 4; ++j) {
            const int ic = i0 + tx*4 + j;
            if (ic < NREL)
                relPg[((size_t)bh * S_ + srow) * NREL + ic] = acc[i][j];
        }
    }
}

// ---------------------------------------------------------------------------
// flash_attn2: deferred softmax (p = exp(s) raw, |s| <= ~16 so no overflow),
// GEMM-style 2D tiling (64 q x 64 k, 4x4 microtile per thread).
// All inner-loop LDS reads are conflict-free (stride-68 transposed tiles).
// Exports unnormalized by-id weights into relP in place ("AW"):
//   middle ids (1..255) <-> unique k; written where computed;
//   tails (0, 256) accumulated in registers, written in epilogue;
//   invalid middle ids (edge rows) zeroed in epilogue.
// ---------------------------------------------------------------------------
__global__ __launch_bounds__(256, 3) void flash_attn2(
        const float* __restrict__ Qw, const float* __restrict__ KwT,
        const float* __restrict__ Vw, float* __restrict__ relP,
        float* __restrict__ Lrow, float* __restrict__ Ow) {
    __shared__ float Qt[64][68];   // Q^T [d][q], loaded once
    __shared__ float KP[64][68];   // K^T [d][k] during QK; then P^T [k][q]
    __shared__ float Vs[64][68];   // V   [k][d]

    const int t = threadIdx.x;
    const int tx = t & 15, ty = t >> 4;
    const int bh = blockIdx.y;
    const int r0 = blockIdx.x * 64;
    const size_t bhS = (size_t)bh * S_;

    // stage Qt (transposed, once)
    #pragma unroll
    for (int it = 0; it < 4; ++it) {
        const int row = (t >> 4) + 16 * it;
        const int db = t & 15;
        float4 q4 = *reinterpret_cast<const float4*>(
            &Qw[(bhS + r0 + row) * 64 + db * 4]);
        Qt[db*4+0][row] = q4.x; Qt[db*4+1][row] = q4.y;
        Qt[db*4+2][row] = q4.z; Qt[db*4+3][row] = q4.w;
    }

    size_t awbase[4];
    #pragma unroll
    for (int i = 0; i < 4; ++i)
        awbase[i] = (bhS + (size_t)(r0 + ty*4 + i)) * NREL;

    float oacc[4][4] = {};
    float lp[4] = {}, w0[4] = {}, w256[4] = {};

    for (int k0 = 0; k0 < S_; k0 += 64) {
        __syncthreads();                     // prev PV done before restage
        #pragma unroll
        for (int it = 0; it < 4; ++it) {
            const int rr = (t >> 4) + 16 * it;
            const int cc = t & 15;
            *reinterpret_cast<float4*>(&KP[rr][cc*4]) =
                *reinterpret_cast<const float4*>(
                    &KwT[((size_t)bh*64 + rr) * S_ + k0 + cc*4]);
            *reinterpret_cast<float4*>(&Vs[rr][cc*4]) =
                *reinterpret_cast<const float4*>(
                    &Vw[(bhS + k0 + rr) * 64 + cc*4]);
        }
        __syncthreads();

        // issue bias gathers early (consumed after the QK loop -> latency hidden)
        float rb[4][4];
        int   idv[4][4];
        #pragma unroll
        for (int i = 0; i < 4; ++i) {
            const int q = r0 + ty*4 + i;
            #pragma unroll
            for (int j = 0; j < 4; ++j) {
                const int kg = k0 + tx*4 + j;
                int rel = q - kg;
                rel = rel > 128 ? 128 : (rel < -128 ? -128 : rel);
                idv[i][j] = rel + 128;
                rb[i][j] = relP[awbase[i] + idv[i][j]];
            }
        }

        // QK^T outer product over d
        float sacc[4][4] = {};
        #pragma unroll 8
        for (int d = 0; d < 64; ++d) {
            float a[4], b[4];
            *reinterpret_cast<float4*>(a) = *reinterpret_cast<float4*>(&Qt[d][ty*4]);
            *reinterpret_cast<float4*>(b) = *reinterpret_cast<float4*>(&KP[d][tx*4]);
            #pragma unroll
            for (int i = 0; i < 4; ++i)
                #pragma unroll
                for (int j = 0; j < 4; ++j)
                    sacc[i][j] += a[i] * b[j];
        }
        __syncthreads();                     // all KP (=K^T) reads done

        // bias + exp + AW export + tail/l accumulation; then P^T into KP
        float p[4][4];
        #pragma unroll
        for (int i = 0; i < 4; ++i) {
            #pragma unroll
            for (int j = 0; j < 4; ++j) {
                const float s = (sacc[i][j] + rb[i][j]) * 0.125f;
                const float pe = __expf(s);
                p[i][j] = pe;
                lp[i] += pe;
                w0[i]   += (idv[i][j] == 0)   ? pe : 0.f;
                w256[i] += (idv[i][j] == 256) ? pe : 0.f;
                if ((unsigned)(idv[i][j] - 1) < 255u)
                    relP[awbase[i] + idv[i][j]] = pe;     // unique (q,id)
            }
        }
        #pragma unroll
        for (int i = 0; i < 4; ++i)
            #pragma unroll
            for (int j = 0; j < 4; ++j)
                KP[tx*4+j][ty*4+i] = p[i][j];            // P^T [k][q]
        __syncthreads();

        // PV outer product over k
        #pragma unroll 8
        for (int k = 0; k < 64; ++k) {
            float a[4], b[4];
            *reinterpret_cast<float4*>(a) = *reinterpret_cast<float4*>(&KP[k][ty*4]);
            *reinterpret_cast<float4*>(b) = *reinterpret_cast<float4*>(&Vs[k][tx*4]);
            #pragma unroll
            for (int i = 0; i < 4; ++i)
                #pragma unroll
                for (int j = 0; j < 4; ++j)
                    oacc[i][j] += a[i] * b[j];
        }
    }

    // epilogue
    const int b = bh >> 4, h = bh & 15;
    #pragma unroll
    for (int i = 0; i < 4; ++i) {
        float l = lp[i], a0 = w0[i], a256 = w256[i];
        #pragma unroll
        for (int off = 1; off < 16; off <<= 1) {
            l    += __shfl_xor(l, off);
            a0   += __shfl_xor(a0, off);
            a256 += __shfl_xor(a256, off);
        }
        const int q = r0 + ty*4 + i;
        if (tx == 0) {
            Lrow[bhS + q]       = l;
            relP[awbase[i] + 0]   = a0;
            relP[awbase[i] + 256] = a256;
        }
        const int lo = q - 1919, hi = q + 129;   // valid middle ids: [max(1,lo), hi)
        if (lo > 1 || hi < 256) {
            for (int id = 1 + tx; id < 256; id += 16)
                if (id < lo || id >= hi) relP[awbase[i] + id] = 0.f;
        }
        const float inv = 1.f / l;
        *reinterpret_cast<float4*>(&Ow[((size_t)b*S_ + q) * H_ + h*64 + tx*4]) =
            make_float4(oacc[i][0]*inv, oacc[i][1]*inv,
                        oacc[i][2]*inv, oacc[i][3]*inv);
    }
}

// ---------------------------------------------------------------------------
// relv_gemm: Ow[bh rows] += (AW[64q x 257] @ Tv[257 x 64]) / Lrow
// ---------------------------------------------------------------------------
__global__ __launch_bounds__(256) void relv_gemm(
        const float* __restrict__ AW, const float* __restrict__ Tv,
        const float* __restrict__ Lrow, float* __restrict__ Ow) {
    __shared__ float Ast[64][68];   // AW^T chunk [kk][q]
    __shared__ float Tvs[64][68];   // Tv chunk   [kk][d]
    const int t = threadIdx.x, tx = t & 15, ty = t >> 4;
    const int bh = blockIdx.x >> 5;
    const int r0 = (blockIdx.x & 31) * 64;
    float acc[4][4] = {};
    for (int c = 0; c < 5; ++c) {
        const int c0 = c * 64;
        __syncthreads();
        #pragma unroll
        for (int it = 0; it < 4; ++it) {
            const int row = (t >> 4) + 16 * it;
            const int db = t & 15;
            const size_t ab = ((size_t)bh*S_ + r0 + row) * NREL + c0 + db*4;
            float4 av = make_float4(0.f, 0.f, 0.f, 0.f);
            if (c < 4) av = *reinterpret_cast<const float4*>(&AW[ab]);
            else if (c0 + db*4 < NREL) av.x = AW[ab];   // only col 256
            Ast[db*4+0][row] = av.x; Ast[db*4+1][row] = av.y;
            Ast[db*4+2][row] = av.z; Ast[db*4+3][row] = av.w;
            float4 tv4 = make_float4(0.f, 0.f, 0.f, 0.f);
            if (c0 + row < NREL)
                tv4 = *reinterpret_cast<const float4*>(&Tv[(size_t)(c0+row)*64 + db*4]);
            *reinterpret_cast<float4*>(&Tvs[row][db*4]) = tv4;
        }
        __syncthreads();
        #pragma unroll 8
        for (int kk = 0; kk < 64; ++kk) {
            float a[4], b[4];
            *reinterpret_cast<float4*>(a) = *reinterpret_cast<float4*>(&Ast[kk][ty*4]);
            *reinterpret_cast<float4*>(b) = *reinterpret_cast<float4*>(&Tvs[kk][tx*4]);
            #pragma unroll
            for (int i = 0; i < 4; ++i)
                #pragma unroll
                for (int j = 0; j < 4; ++j)
                    acc[i][j] += a[i] * b[j];
        }
    }
    const int b = bh >> 4, h = bh & 15;
    #pragma unroll
    for (int i = 0; i < 4; ++i) {
        const int q = r0 + ty*4 + i;
        const float inv = 1.f / Lrow[(size_t)bh*S_ + q];
        float4* op = reinterpret_cast<float4*>(
            &Ow[((size_t)b*S_ + q) * H_ + h*64 + tx*4]);
        float4 o = *op;
        o.x += acc[i][0]*inv; o.y += acc[i][1]*inv;
        o.z += acc[i][2]*inv; o.w += acc[i][3]*inv;
        *op = o;
    }
}

// ---------------------------------------------------------------------------
extern "C" void kernel_launch(void* const* d_in, const int* in_sizes, int n_in,
                              void* d_out, int out_size, void* d_ws, size_t ws_size,
                              hipStream_t stream) {
    const float* query = (const float*)d_in[0];
    const float* key_  = (const float*)d_in[1];
    const float* value = (const float*)d_in[2];
    const float* Wq = (const float*)d_in[3];
    const float* bq = (const float*)d_in[4];
    const float* Wk = (const float*)d_in[5];
    const float* bk = (const float*)d_in[6];
    const float* Wv = (const float*)d_in[7];
    const float* bv = (const float*)d_in[8];
    const float* Wo = (const float*)d_in[9];
    const float* bo = (const float*)d_in[10];
    const float* Tk = (const float*)d_in[11];
    const float* Tv = (const float*)d_in[12];

    float* ws = (float*)d_ws;
    const size_t QKV = (size_t)32 * S_ * 64;          // 4,194,304 floats
    float* Qw   = ws;
    float* KwT  = Qw + QKV;
    float* Vw   = KwT + QKV;
    float* relP = Vw + QKV;                            // doubles as AW
    float* Ow   = relP + (size_t)32 * S_ * NREL;
    float* Lrow = Ow + QKV;                            // 65,536 floats

    const dim3 gemmGrid(16, 64), blk(256);
    proj_gemm<0><<<gemmGrid, blk, 0, stream>>>(query, Wq, bq, Qw);
    proj_gemm<2><<<gemmGrid, blk, 0, stream>>>(key_,  Wk, bk, KwT);
    proj_gemm<0><<<gemmGrid, blk, 0, stream>>>(value, Wv, bv, Vw);
    relp_gemm<<<dim3(5, 32, 32), blk, 0, stream>>>(Qw, Tk, relP);
    flash_attn2<<<dim3(32, 32), blk, 0, stream>>>(Qw, KwT, Vw, relP, Lrow, Ow);
    relv_gemm<<<dim3(1024), blk, 0, stream>>>(relP, Tv, Lrow, Ow);
    proj_gemm<1><<<gemmGrid, blk, 0, stream>>>(Ow, Wo, bo, (float*)d_out);
}

// Round 4
// 1005.135 us; speedup vs baseline: 6.3573x; 1.2273x over previous
//
#include <hip/hip_runtime.h>
#include <math.h>
#include <cstddef>

// B=2, S=2048, H=1024, NUM_HEADS=16, hd=64, MAX_REL=128 -> 257 table rows
// Workspace (~126.4 MB):
//   Qw   [32][2048][64] f32   (Q head layout, for relp_gemm)
//   relP [32][2048][257] f32  (bias table; overwritten in place with AW)
//   Ow   [2][2048][1024] f32  (attention output)
//   Lrow [32][2048] f32       (softmax denominators)
//   Qb   [32][2048][64] bf16  (Q head layout)
//   Kb   [32][2048][64] bf16  (K head layout, row-major)
//   Vt   [32][64][2048] bf16  (V head layout, TRANSPOSED d-major)

#define S_ 2048
#define H_ 1024
#define NREL 257

typedef __attribute__((ext_vector_type(8))) short bf16x8;
typedef __attribute__((ext_vector_type(4))) float f32x4;

__device__ __forceinline__ unsigned short f2bf(float x) {
    unsigned u = __builtin_bit_cast(unsigned, x);
    return (unsigned short)((u + 0x7FFFu + ((u >> 16) & 1u)) >> 16);
}

// ---------------------------------------------------------------------------
// GEMM: Y = X[4096,1024] @ W[1024,1024] + bias
// MODE 0: Q -> fp32 head layout Y + bf16 head layout Yb
// MODE 4: K -> bf16 head layout Yb only
// MODE 3: V -> bf16 TRANSPOSED [bh][d][2048 s] Yb only
// MODE 1: flat fp32 [4096,1024] Y (output projection)
// ---------------------------------------------------------------------------
template<int MODE>
__global__ __launch_bounds__(256) void proj_gemm(const float* __restrict__ X,
        const float* __restrict__ W, const float* __restrict__ bias,
        float* __restrict__ Y, unsigned short* __restrict__ Yb) {
    const int K = H_, N = H_;
    __shared__ float As[32][68];   // [kk][m] (transposed A tile)
    __shared__ float Bs[32][64];   // [kk][n]
    const int m0 = blockIdx.y * 64;
    const int n0 = blockIdx.x * 64;
    const int t = threadIdx.x;
    const int tx = t & 15, ty = t >> 4;
    float acc[4][4] = {};
    for (int k0 = 0; k0 < K; k0 += 32) {
        __syncthreads();
        #pragma unroll
        for (int j = 0; j < 2; ++j) {           // A tile 64x32
            int f = t + j * 256;
            int row = f >> 3, cb = f & 7;
            float4 a4 = *reinterpret_cast<const float4*>(
                &X[(size_t)(m0 + row) * K + k0 + cb * 4]);
            As[cb*4+0][row] = a4.x; As[cb*4+1][row] = a4.y;
            As[cb*4+2][row] = a4.z; As[cb*4+3][row] = a4.w;
        }
        #pragma unroll
        for (int j = 0; j < 2; ++j) {           // B tile 32x64
            int f = t + j * 256;
            int kk = f >> 4, nb = f & 15;
            *reinterpret_cast<float4*>(&Bs[kk][nb*4]) =
                *reinterpret_cast<const float4*>(&W[(size_t)(k0 + kk) * N + n0 + nb * 4]);
        }
        __syncthreads();
        #pragma unroll
        for (int kk = 0; kk < 32; ++kk) {
            float a[4], b[4];
            *reinterpret_cast<float4*>(a) = *reinterpret_cast<float4*>(&As[kk][ty*4]);
            *reinterpret_cast<float4*>(b) = *reinterpret_cast<float4*>(&Bs[kk][tx*4]);
            #pragma unroll
            for (int i = 0; i < 4; ++i)
                #pragma unroll
                for (int j = 0; j < 4; ++j)
                    acc[i][j] += a[i] * b[j];
        }
    }
    const float4 b4 = *reinterpret_cast<const float4*>(&bias[n0 + tx*4]);
    const float bb[4] = {b4.x, b4.y, b4.z, b4.w};
    #pragma unroll
    for (int i = 0; i < 4; ++i) {
        const int row = m0 + ty*4 + i;
        float res[4];
        #pragma unroll
        for (int j = 0; j < 4; ++j) res[j] = acc[i][j] + bb[j];
        if (MODE == 1) {
            *reinterpret_cast<float4*>(&Y[(size_t)row * N + n0 + tx*4]) =
                make_float4(res[0], res[1], res[2], res[3]);
        } else {
            const int b = row >> 11, s = row & 2047;
            const int h = blockIdx.x;            // heads are 64-col aligned
            if (MODE == 0) {
                const size_t base = (((size_t)b*16 + h)*S_ + s)*64 + tx*4;
                *reinterpret_cast<float4*>(&Y[base]) =
                    make_float4(res[0], res[1], res[2], res[3]);
                ushort4 o;
                o.x = f2bf(res[0]); o.y = f2bf(res[1]);
                o.z = f2bf(res[2]); o.w = f2bf(res[3]);
                *reinterpret_cast<ushort4*>(&Yb[base]) = o;
            } else if (MODE == 4) {
                const size_t base = (((size_t)b*16 + h)*S_ + s)*64 + tx*4;
                ushort4 o;
                o.x = f2bf(res[0]); o.y = f2bf(res[1]);
                o.z = f2bf(res[2]); o.w = f2bf(res[3]);
                *reinterpret_cast<ushort4*>(&Yb[base]) = o;
            } else {   // MODE 3: V transposed bf16 [bh][d][s]
                const size_t base = ((size_t)b*16 + h) * 64;
                #pragma unroll
                for (int j = 0; j < 4; ++j)
                    Yb[(base + tx*4 + j) * S_ + s] = f2bf(res[j]);
            }
        }
    }
}

// ---------------------------------------------------------------------------
// relP[bh][s][i] = sum_d Qw[bh][s][d] * Tk[i][d],  i in [0,257)
// ---------------------------------------------------------------------------
__global__ __launch_bounds__(256) void relp_gemm(const float* __restrict__ Qw,
        const float* __restrict__ Tk, float* __restrict__ relPg) {
    __shared__ float As[64][68];   // [d][srow]
    __shared__ float Bs[64][68];   // [d][i]
    const int bh = blockIdx.z;
    const int s0 = blockIdx.y * 64;
    const int i0 = blockIdx.x * 64;
    const int t = threadIdx.x;
    const int tx = t & 15, ty = t >> 4;
    #pragma unroll
    for (int j = 0; j < 4; ++j) {
        int f = t + j * 256;
        int row = f >> 4, db = f & 15;
        float4 q4 = *reinterpret_cast<const float4*>(
            &Qw[((size_t)bh * S_ + s0 + row) * 64 + db * 4]);
        As[db*4+0][row] = q4.x; As[db*4+1][row] = q4.y;
        As[db*4+2][row] = q4.z; As[db*4+3][row] = q4.w;
        int i = i0 + row;
        float4 t4 = make_float4(0.f, 0.f, 0.f, 0.f);
        if (i < NREL)
            t4 = *reinterpret_cast<const float4*>(&Tk[(size_t)i * 64 + db * 4]);
        Bs[db*4+0][row] = t4.x; Bs[db*4+1][row] = t4.y;
        Bs[db*4+2][row] = t4.z; Bs[db*4+3][row] = t4.w;
    }
    __syncthreads();
    float acc[4][4] = {};
    #pragma unroll 8
    for (int d = 0; d < 64; ++d) {
        float a[4], b[4];
        *reinterpret_cast<float4*>(a) = *reinterpret_cast<float4*>(&As[d][ty*4]);
        *reinterpret_cast<float4*>(b) = *reinterpret_cast<float4*>(&Bs[d][tx*4]);
        #pragma unroll
        for (int i = 0; i < 4; ++i)
            #pragma unroll
            for (int j = 0; j < 4; ++j)
                acc[i][j] += a[i] * b[j];
    }
    #pragma unroll
    for (int i = 0; i < 4; ++i) {
        const int srow = s0 + ty*4 + i;
        #pragma unroll
        for (int j = 0; j < 4; ++j) {
            const int ic = i0 + tx*4 + j;
            if (ic < NREL)
                relPg[((size_t)bh * S_ + srow) * NREL + ic] = acc[i][j];
        }
    }
}

// ---------------------------------------------------------------------------
// flash_attn3: bf16 MFMA attention core, fp32 deferred softmax.
// Block = 256 thr = 4 waves; wave w owns q rows [r0+w*16, +16).
// QK^T: A = Q frags (registers, loaded once), B = K rows direct from global.
// P -> per-wave LDS transpose (bf16) -> A frags for PV; B = Vt rows (global).
// MFMA layouts (16x16x32 bf16): A row=lane%16, k=8*(lane/16)+j (contig 8);
// B col=lane%16, same k packing; C/D col=lane&15, row=4*(lane>>4)+reg [m89].
// AW export identical to round-3 logic (unique (q,id)<->k for middle ids).
// ---------------------------------------------------------------------------
__global__ __launch_bounds__(256) void flash_attn3(
        const unsigned short* __restrict__ Qb, const unsigned short* __restrict__ Kb,
        const unsigned short* __restrict__ Vt, float* __restrict__ relP,
        float* __restrict__ Lrow, float* __restrict__ Ow) {
    __shared__ unsigned short P_lds[4][16][72];   // per-wave, stride 72 (144B, 16B-aligned)

    const int t = threadIdx.x;
    const int w = t >> 6, l = t & 63;
    const int lq = l & 15, lg = l >> 4;
    const int bh = blockIdx.y;
    const int r0 = blockIdx.x * 64;
    const size_t bhS = (size_t)bh * S_;

    // Q A-fragments (held in registers for all 32 k-tiles)
    const unsigned short* qp = Qb + (bhS + r0 + w*16 + lq) * 64 + 8*lg;
    const bf16x8 qa0 = *reinterpret_cast<const bf16x8*>(qp);
    const bf16x8 qa1 = *reinterpret_cast<const bf16x8*>(qp + 32);

    const int qrow = r0 + w*16 + 4*lg;            // + reg
    size_t awb[4];
    #pragma unroll
    for (int r = 0; r < 4; ++r) awb[r] = (bhS + qrow + r) * NREL;

    f32x4 oacc[4];
    #pragma unroll
    for (int dt = 0; dt < 4; ++dt) oacc[dt] = (f32x4){0.f, 0.f, 0.f, 0.f};
    float lp[4]    = {0.f, 0.f, 0.f, 0.f};
    float w0a[4]   = {0.f, 0.f, 0.f, 0.f};
    float w256a[4] = {0.f, 0.f, 0.f, 0.f};

    const unsigned short* kb_base = Kb + (bhS + lq) * 64 + 8*lg;
    const unsigned short* vt_base = Vt + ((size_t)bh*64 + lq) * 2048 + 8*lg;

    for (int k0 = 0; k0 < S_; k0 += 64) {
        __syncthreads();   // prev iteration's P reads done before rewriting P_lds

        // bias gathers issued early (consumed after QK MFMAs)
        float rb[4][4];
        int   idv[4][4];
        #pragma unroll
        for (int kt = 0; kt < 4; ++kt) {
            const int kg = k0 + kt*16 + lq;
            #pragma unroll
            for (int r = 0; r < 4; ++r) {
                int rel = (qrow + r) - kg;
                rel = rel > 128 ? 128 : (rel < -128 ? -128 : rel);
                idv[kt][r] = rel + 128;
                rb[kt][r] = relP[awb[r] + idv[kt][r]];
            }
        }

        // QK^T: 8 MFMAs (4 k-subtiles x 2 d-frags)
        f32x4 sacc[4];
        #pragma unroll
        for (int kt = 0; kt < 4; ++kt) {
            const unsigned short* kp = kb_base + (size_t)(k0 + kt*16) * 64;
            bf16x8 kb0 = *reinterpret_cast<const bf16x8*>(kp);
            bf16x8 kb1 = *reinterpret_cast<const bf16x8*>(kp + 32);
            f32x4 s = (f32x4){0.f, 0.f, 0.f, 0.f};
            s = __builtin_amdgcn_mfma_f32_16x16x32_bf16(qa0, kb0, s, 0, 0, 0);
            s = __builtin_amdgcn_mfma_f32_16x16x32_bf16(qa1, kb1, s, 0, 0, 0);
            sacc[kt] = s;
        }

        // softmax weights + AW export + P (bf16) into per-wave LDS
        #pragma unroll
        for (int kt = 0; kt < 4; ++kt) {
            #pragma unroll
            for (int r = 0; r < 4; ++r) {
                const int id = idv[kt][r];
                const float s = (sacc[kt][r] + rb[kt][r]) * 0.125f;
                const float pe = __expf(s);
                lp[r] += pe;
                w0a[r]   += (id == 0)   ? pe : 0.f;
                w256a[r] += (id == 256) ? pe : 0.f;
                if ((unsigned)(id - 1) < 255u)
                    relP[awb[r] + id] = pe;          // unique (q,id) writer
                P_lds[w][4*lg + r][kt*16 + lq] = f2bf(pe);
            }
        }
        __syncthreads();   // cross-lane P visibility

        // P A-frags + V B-frags -> PV: 8 MFMAs (4 d-subtiles x 2 k-frags)
        const bf16x8 pa0 = *reinterpret_cast<const bf16x8*>(&P_lds[w][lq][8*lg]);
        const bf16x8 pa1 = *reinterpret_cast<const bf16x8*>(&P_lds[w][lq][32 + 8*lg]);
        #pragma unroll
        for (int dt = 0; dt < 4; ++dt) {
            const unsigned short* vp = vt_base + (size_t)(dt*16)*2048 + k0;
            bf16x8 vb0 = *reinterpret_cast<const bf16x8*>(vp);
            bf16x8 vb1 = *reinterpret_cast<const bf16x8*>(vp + 32);
            oacc[dt] = __builtin_amdgcn_mfma_f32_16x16x32_bf16(pa0, vb0, oacc[dt], 0, 0, 0);
            oacc[dt] = __builtin_amdgcn_mfma_f32_16x16x32_bf16(pa1, vb1, oacc[dt], 0, 0, 0);
        }
    }

    // epilogue: reduce l and tails over the 16 lanes sharing each row group
    const int b = bh >> 4, h = bh & 15;
    #pragma unroll
    for (int r = 0; r < 4; ++r) {
        float ls = lp[r], a0 = w0a[r], a2 = w256a[r];
        #pragma unroll
        for (int off = 1; off < 16; off <<= 1) {
            ls += __shfl_xor(ls, off);
            a0 += __shfl_xor(a0, off);
            a2 += __shfl_xor(a2, off);
        }
        const int q = qrow + r;
        if (lq == 0) {
            Lrow[bhS + q]       = ls;
            relP[awb[r] + 0]    = a0;
            relP[awb[r] + 256]  = a2;
        }
        const int lo = q - 1919, hi = q + 129;   // valid middle ids: [max(1,lo), min(256,hi))
        if (lo > 1 || hi < 256) {
            for (int id = 1 + lq; id < 256; id += 16)
                if (id < lo || id >= hi) relP[awb[r] + id] = 0.f;
        }
        const float inv = 1.f / ls;
        #pragma unroll
        for (int dt = 0; dt < 4; ++dt)
            Ow[((size_t)b*S_ + q)*H_ + h*64 + dt*16 + lq] = oacc[dt][r] * inv;
    }
}

// ---------------------------------------------------------------------------
// relv_gemm: Ow[bh rows] += (AW[64q x 257] @ Tv[257 x 64]) / Lrow
// ---------------------------------------------------------------------------
__global__ __launch_bounds__(256) void relv_gemm(
        const float* __restrict__ AW, const float* __restrict__ Tv,
        const float* __restrict__ Lrow, float* __restrict__ Ow) {
    __shared__ float Ast[64][68];   // AW^T chunk [kk][q]
    __shared__ float Tvs[64][68];   // Tv chunk   [kk][d]
    const int t = threadIdx.x, tx = t & 15, ty = t >> 4;
    const int bh = blockIdx.x >> 5;
    const int r0 = (blockIdx.x & 31) * 64;
    float acc[4][4] = {};
    for (int c = 0; c < 5; ++c) {
        const int c0 = c * 64;
        __syncthreads();
        #pragma unroll
        for (int it = 0; it < 4; ++it) {
            const int row = (t >> 4) + 16 * it;
            const int db = t & 15;
            const size_t ab = ((size_t)bh*S_ + r0 + row) * NREL + c0 + db*4;
            float4 av = make_float4(0.f, 0.f, 0.f, 0.f);
            if (c < 4) av = *reinterpret_cast<const float4*>(&AW[ab]);
            else if (c0 + db*4 < NREL) av.x = AW[ab];   // only col 256
            Ast[db*4+0][row] = av.x; Ast[db*4+1][row] = av.y;
            Ast[db*4+2][row] = av.z; Ast[db*4+3][row] = av.w;
            float4 tv4 = make_float4(0.f, 0.f, 0.f, 0.f);
            if (c0 + row < NREL)
                tv4 = *reinterpret_cast<const float4*>(&Tv[(size_t)(c0+row)*64 + db*4]);
            *reinterpret_cast<float4*>(&Tvs[row][db*4]) = tv4;
        }
        __syncthreads();
        #pragma unroll 8
        for (int kk = 0; kk < 64; ++kk) {
            float a[4], b[4];
            *reinterpret_cast<float4*>(a) = *reinterpret_cast<float4*>(&Ast[kk][ty*4]);
            *reinterpret_cast<float4*>(b) = *reinterpret_cast<float4*>(&Tvs[kk][tx*4]);
            #pragma unroll
            for (int i = 0; i < 4; ++i)
                #pragma unroll
                for (int j = 0; j < 4; ++j)
                    acc[i][j] += a[i] * b[j];
        }
    }
    const int b = bh >> 4, h = bh & 15;
    #pragma unroll
    for (int i = 0; i < 4; ++i) {
        const int q = r0 + ty*4 + i;
        const float inv = 1.f / Lrow[(size_t)bh*S_ + q];
        float4* op = reinterpret_cast<float4*>(
            &Ow[((size_t)b*S_ + q) * H_ + h*64 + tx*4]);
        float4 o = *op;
        o.x += acc[i][0]*inv; o.y += acc[i][1]*inv;
        o.z += acc[i][2]*inv; o.w += acc[i][3]*inv;
        *op = o;
    }
}

// ---------------------------------------------------------------------------
extern "C" void kernel_launch(void* const* d_in, const int* in_sizes, int n_in,
                              void* d_out, int out_size, void* d_ws, size_t ws_size,
                              hipStream_t stream) {
    const float* query = (const float*)d_in[0];
    const float* key_  = (const float*)d_in[1];
    const float* value = (const float*)d_in[2];
    const float* Wq = (const float*)d_in[3];
    const float* bq = (const float*)d_in[4];
    const float* Wk = (const float*)d_in[5];
    const float* bk = (const float*)d_in[6];
    const float* Wv = (const float*)d_in[7];
    const float* bv = (const float*)d_in[8];
    const float* Wo = (const float*)d_in[9];
    const float* bo = (const float*)d_in[10];
    const float* Tk = (const float*)d_in[11];
    const float* Tv = (const float*)d_in[12];

    float* ws = (float*)d_ws;
    float* Qw   = ws;                                  //  4,194,304 f
    float* relP = Qw + (size_t)4194304;                // 16,842,752 f
    float* Ow   = relP + (size_t)16842752;             //  4,194,304 f
    float* Lrow = Ow + (size_t)4194304;                //     65,536 f
    unsigned short* Qb = (unsigned short*)(Lrow + 65536);
    unsigned short* Kb = Qb + (size_t)4194304;
    unsigned short* Vt = Kb + (size_t)4194304;

    const dim3 gemmGrid(16, 64), blk(256);
    proj_gemm<0><<<gemmGrid, blk, 0, stream>>>(query, Wq, bq, Qw, Qb);
    proj_gemm<4><<<gemmGrid, blk, 0, stream>>>(key_,  Wk, bk, nullptr, Kb);
    proj_gemm<3><<<gemmGrid, blk, 0, stream>>>(value, Wv, bv, nullptr, Vt);
    relp_gemm<<<dim3(5, 32, 32), blk, 0, stream>>>(Qw, Tk, relP);
    flash_attn3<<<dim3(32, 32), blk, 0, stream>>>(Qb, Kb, Vt, relP, Lrow, Ow);
    relv_gemm<<<dim3(1024), blk, 0, stream>>>(relP, Tv, Lrow, Ow);
    proj_gemm<1><<<gemmGrid, blk, 0, stream>>>(Ow, Wo, bo, (float*)d_out, nullptr);
}

// Round 5
// 1002.594 us; speedup vs baseline: 6.3734x; 1.0025x over previous
//
#include <hip/hip_runtime.h>
#include <math.h>
#include <cstddef>

// B=2, S=2048, H=1024, NUM_HEADS=16, hd=64, MAX_REL=128 -> 257 table rows
// Workspace (~126.1 MB):
//   Qw   [32][2048][64] f32   (Q head layout, for relp_gemm)
//   relP [32][2048][257] f32  (bias table, read-only in flash)
//   Ow   [2][2048][1024] f32  (attention output)
//   Qb   [32][2048][64] bf16
//   Kb   [32][2048][64] bf16
//   Vt   [32][64][2048] bf16  (V transposed d-major)
//   TvbT [64][256] bf16       (Tv transposed, ids 0..255)

#define S_ 2048
#define H_ 1024
#define NREL 257

typedef __attribute__((ext_vector_type(8))) short bf16x8;
typedef __attribute__((ext_vector_type(4))) float f32x4;

__device__ __forceinline__ unsigned short f2bf(float x) {
    unsigned u = __builtin_bit_cast(unsigned, x);
    return (unsigned short)((u + 0x7FFFu + ((u >> 16) & 1u)) >> 16);
}

// ---------------------------------------------------------------------------
// GEMM: Y = X[4096,1024] @ W[1024,1024] + bias
// MODE 0: Q -> fp32 head layout Y + bf16 head layout Yb
// MODE 4: K -> bf16 head layout Yb only
// MODE 3: V -> bf16 TRANSPOSED [bh][d][2048 s] Yb only
// MODE 1: flat fp32 [4096,1024] Y (output projection)
// ---------------------------------------------------------------------------
template<int MODE>
__global__ __launch_bounds__(256) void proj_gemm(const float* __restrict__ X,
        const float* __restrict__ W, const float* __restrict__ bias,
        float* __restrict__ Y, unsigned short* __restrict__ Yb) {
    const int K = H_, N = H_;
    __shared__ float As[32][68];   // [kk][m] (transposed A tile)
    __shared__ float Bs[32][64];   // [kk][n]
    const int m0 = blockIdx.y * 64;
    const int n0 = blockIdx.x * 64;
    const int t = threadIdx.x;
    const int tx = t & 15, ty = t >> 4;
    float acc[4][4] = {};
    for (int k0 = 0; k0 < K; k0 += 32) {
        __syncthreads();
        #pragma unroll
        for (int j = 0; j < 2; ++j) {           // A tile 64x32
            int f = t + j * 256;
            int row = f >> 3, cb = f & 7;
            float4 a4 = *reinterpret_cast<const float4*>(
                &X[(size_t)(m0 + row) * K + k0 + cb * 4]);
            As[cb*4+0][row] = a4.x; As[cb*4+1][row] = a4.y;
            As[cb*4+2][row] = a4.z; As[cb*4+3][row] = a4.w;
        }
        #pragma unroll
        for (int j = 0; j < 2; ++j) {           // B tile 32x64
            int f = t + j * 256;
            int kk = f >> 4, nb = f & 15;
            *reinterpret_cast<float4*>(&Bs[kk][nb*4]) =
                *reinterpret_cast<const float4*>(&W[(size_t)(k0 + kk) * N + n0 + nb * 4]);
        }
        __syncthreads();
        #pragma unroll
        for (int kk = 0; kk < 32; ++kk) {
            float a[4], b[4];
            *reinterpret_cast<float4*>(a) = *reinterpret_cast<float4*>(&As[kk][ty*4]);
            *reinterpret_cast<float4*>(b) = *reinterpret_cast<float4*>(&Bs[kk][tx*4]);
            #pragma unroll
            for (int i = 0; i < 4; ++i)
                #pragma unroll
                for (int j = 0; j < 4; ++j)
                    acc[i][j] += a[i] * b[j];
        }
    }
    const float4 b4 = *reinterpret_cast<const float4*>(&bias[n0 + tx*4]);
    const float bb[4] = {b4.x, b4.y, b4.z, b4.w};
    #pragma unroll
    for (int i = 0; i < 4; ++i) {
        const int row = m0 + ty*4 + i;
        float res[4];
        #pragma unroll
        for (int j = 0; j < 4; ++j) res[j] = acc[i][j] + bb[j];
        if (MODE == 1) {
            *reinterpret_cast<float4*>(&Y[(size_t)row * N + n0 + tx*4]) =
                make_float4(res[0], res[1], res[2], res[3]);
        } else {
            const int b = row >> 11, s = row & 2047;
            const int h = blockIdx.x;            // heads are 64-col aligned
            if (MODE == 0) {
                const size_t base = (((size_t)b*16 + h)*S_ + s)*64 + tx*4;
                *reinterpret_cast<float4*>(&Y[base]) =
                    make_float4(res[0], res[1], res[2], res[3]);
                ushort4 o;
                o.x = f2bf(res[0]); o.y = f2bf(res[1]);
                o.z = f2bf(res[2]); o.w = f2bf(res[3]);
                *reinterpret_cast<ushort4*>(&Yb[base]) = o;
            } else if (MODE == 4) {
                const size_t base = (((size_t)b*16 + h)*S_ + s)*64 + tx*4;
                ushort4 o;
                o.x = f2bf(res[0]); o.y = f2bf(res[1]);
                o.z = f2bf(res[2]); o.w = f2bf(res[3]);
                *reinterpret_cast<ushort4*>(&Yb[base]) = o;
            } else {   // MODE 3: V transposed bf16 [bh][d][s]
                const size_t base = ((size_t)b*16 + h) * 64;
                #pragma unroll
                for (int j = 0; j < 4; ++j)
                    Yb[(base + tx*4 + j) * S_ + s] = f2bf(res[j]);
            }
        }
    }
}

// ---------------------------------------------------------------------------
// relP[bh][s][i] = sum_d Qw[bh][s][d] * Tk[i][d],  i in [0,257)
// ---------------------------------------------------------------------------
__global__ __launch_bounds__(256) void relp_gemm(const float* __restrict__ Qw,
        const float* __restrict__ Tk, float* __restrict__ relPg) {
    __shared__ float As[64][68];   // [d][srow]
    __shared__ float Bs[64][68];   // [d][i]
    const int bh = blockIdx.z;
    const int s0 = blockIdx.y * 64;
    const int i0 = blockIdx.x * 64;
    const int t = threadIdx.x;
    const int tx = t & 15, ty = t >> 4;
    #pragma unroll
    for (int j = 0; j < 4; ++j) {
        int f = t + j * 256;
        int row = f >> 4, db = f & 15;
        float4 q4 = *reinterpret_cast<const float4*>(
            &Qw[((size_t)bh * S_ + s0 + row) * 64 + db * 4]);
        As[db*4+0][row] = q4.x; As[db*4+1][row] = q4.y;
        As[db*4+2][row] = q4.z; As[db*4+3][row] = q4.w;
        int i = i0 + row;
        float4 t4 = make_float4(0.f, 0.f, 0.f, 0.f);
        if (i < NREL)
            t4 = *reinterpret_cast<const float4*>(&Tk[(size_t)i * 64 + db * 4]);
        Bs[db*4+0][row] = t4.x; Bs[db*4+1][row] = t4.y;
        Bs[db*4+2][row] = t4.z; Bs[db*4+3][row] = t4.w;
    }
    __syncthreads();
    float acc[4][4] = {};
    #pragma unroll 8
    for (int d = 0; d < 64; ++d) {
        float a[4], b[4];
        *reinterpret_cast<float4*>(a) = *reinterpret_cast<float4*>(&As[d][ty*4]);
        *reinterpret_cast<float4*>(b) = *reinterpret_cast<float4*>(&Bs[d][tx*4]);
        #pragma unroll
        for (int i = 0; i < 4; ++i)
            #pragma unroll
            for (int j = 0; j < 4; ++j)
                acc[i][j] += a[i] * b[j];
    }
    #pragma unroll
    for (int i = 0; i < 4; ++i) {
        const int srow = s0 + ty*4 + i;
        #pragma unroll
        for (int j = 0; j < 4; ++j) {
            const int ic = i0 + tx*4 + j;
            if (ic < NREL)
                relPg[((size_t)bh * S_ + srow) * NREL + ic] = acc[i][j];
        }
    }
}

// ---------------------------------------------------------------------------
// TvbT[d][id] = bf16(Tv[id][d]) for id in [0,256): transposed rel_value table
// ---------------------------------------------------------------------------
__global__ __launch_bounds__(256) void tvb_prep(const float* __restrict__ Tv,
        unsigned short* __restrict__ TvbT) {
    const int idx = blockIdx.x * 256 + threadIdx.x;   // 16384 total
    const int d = idx >> 8, id = idx & 255;
    TvbT[idx] = f2bf(Tv[(size_t)id * 64 + d]);
}

// ---------------------------------------------------------------------------
// flash_attn4: bf16 MFMA attention core + fused rel_v, fp32 deferred softmax.
// Band structure: for q-block [r0,r0+64), only k-tiles with |k0-r0|<192 can
// have middle ids (5 of 32). LEFT tiles: id=256 uniform; RIGHT: id=0 uniform;
// tail biases live in registers -> zero relP gathers outside the band.
// AW (unnormalized weights by id, middle band only) accumulates in swizzled
// LDS [64][256] bf16; epilogue folds AW@TvbT into oacc via 32 MFMAs; tails
// added as rank-1 register terms. No relv pass, no Lrow, no scattered
// global writes.
// ---------------------------------------------------------------------------
__global__ __launch_bounds__(256) void flash_attn4(
        const unsigned short* __restrict__ Qb, const unsigned short* __restrict__ Kb,
        const unsigned short* __restrict__ Vt, const float* __restrict__ relP,
        const unsigned short* __restrict__ TvbT, const float* __restrict__ Tv,
        float* __restrict__ Ow) {
    __shared__ __align__(16) unsigned short AW[64][256];        // 32 KB, swizzled cols
    __shared__ __align__(16) unsigned short P_lds[4][16][72];   // 9 KB

    const int t = threadIdx.x;
    const int w = t >> 6, l = t & 63;
    const int lq = l & 15, lg = l >> 4;
    const int bh = blockIdx.y;
    const int r0 = blockIdx.x * 64;
    const size_t bhS = (size_t)bh * S_;

    // zero AW (2048 x 16B)
    #pragma unroll
    for (int i = 0; i < 8; ++i)
        reinterpret_cast<uint4*>(AW)[t + 256*i] = make_uint4(0,0,0,0);

    // Q A-fragments (registers, reused all 32 k-tiles)
    const unsigned short* qp = Qb + (bhS + r0 + w*16 + lq) * 64 + 8*lg;
    const bf16x8 qa0 = *reinterpret_cast<const bf16x8*>(qp);
    const bf16x8 qa1 = *reinterpret_cast<const bf16x8*>(qp + 32);

    const int qrow = r0 + w*16 + 4*lg;            // + r
    size_t awb[4];
    float b0[4], b256[4];
    #pragma unroll
    for (int r = 0; r < 4; ++r) {
        awb[r] = (bhS + qrow + r) * NREL;
        b0[r]   = relP[awb[r] + 0];
        b256[r] = relP[awb[r] + 256];
    }

    f32x4 oacc[4];
    #pragma unroll
    for (int dt = 0; dt < 4; ++dt) oacc[dt] = (f32x4){0.f, 0.f, 0.f, 0.f};
    float lp[4]    = {0.f, 0.f, 0.f, 0.f};
    float w0a[4]   = {0.f, 0.f, 0.f, 0.f};
    float w256a[4] = {0.f, 0.f, 0.f, 0.f};

    const unsigned short* kb_base = Kb + (bhS + lq) * 64 + 8*lg;
    const unsigned short* vt_base = Vt + ((size_t)bh*64 + lq) * 2048 + 8*lg;

    for (int k0 = 0; k0 < S_; k0 += 64) {
        __syncthreads();   // prev tile's P reads done before rewriting P_lds

        // QK^T: 8 MFMAs (4 k-subtiles x 2 d-frags)
        f32x4 sacc[4];
        #pragma unroll
        for (int kt = 0; kt < 4; ++kt) {
            const unsigned short* kp = kb_base + (size_t)(k0 + kt*16) * 64;
            bf16x8 kb0 = *reinterpret_cast<const bf16x8*>(kp);
            bf16x8 kb1 = *reinterpret_cast<const bf16x8*>(kp + 32);
            f32x4 s = (f32x4){0.f, 0.f, 0.f, 0.f};
            s = __builtin_amdgcn_mfma_f32_16x16x32_bf16(qa0, kb0, s, 0, 0, 0);
            s = __builtin_amdgcn_mfma_f32_16x16x32_bf16(qa1, kb1, s, 0, 0, 0);
            sacc[kt] = s;
        }

        const int d0 = k0 - r0;                    // block-uniform branch
        if (d0 <= -192) {                          // LEFT: id = 256 everywhere
            #pragma unroll
            for (int kt = 0; kt < 4; ++kt)
                #pragma unroll
                for (int r = 0; r < 4; ++r) {
                    const float pe = __expf((sacc[kt][r] + b256[r]) * 0.125f);
                    lp[r] += pe; w256a[r] += pe;
                    P_lds[w][4*lg + r][kt*16 + lq] = f2bf(pe);
                }
        } else if (d0 >= 192) {                    // RIGHT: id = 0 everywhere
            #pragma unroll
            for (int kt = 0; kt < 4; ++kt)
                #pragma unroll
                for (int r = 0; r < 4; ++r) {
                    const float pe = __expf((sacc[kt][r] + b0[r]) * 0.125f);
                    lp[r] += pe; w0a[r] += pe;
                    P_lds[w][4*lg + r][kt*16 + lq] = f2bf(pe);
                }
        } else {                                   // BAND (5 tiles max)
            #pragma unroll
            for (int kt = 0; kt < 4; ++kt) {
                const int kg = k0 + kt*16 + lq;
                #pragma unroll
                for (int r = 0; r < 4; ++r) {
                    int rel = (qrow + r) - kg;
                    rel = rel > 128 ? 128 : (rel < -128 ? -128 : rel);
                    const int id = rel + 128;
                    const bool mid = (unsigned)(id - 1) < 255u;
                    const float bias = mid ? relP[awb[r] + id]
                                           : (id == 0 ? b0[r] : b256[r]);
                    const float pe = __expf((sacc[kt][r] + bias) * 0.125f);
                    lp[r] += pe;
                    if (id == 0) w0a[r] += pe;
                    else if (id == 256) w256a[r] += pe;
                    else {
                        const int row = w*16 + 4*lg + r;
                        AW[row][((((unsigned)id >> 3) ^ (row & 7u)) << 3) + (id & 7)]
                            = f2bf(pe);            // unique (q,id) writer
                    }
                    P_lds[w][4*lg + r][kt*16 + lq] = f2bf(pe);
                }
            }
        }
        __syncthreads();   // cross-lane P visibility

        // PV: 8 MFMAs (4 d-subtiles x 2 k-frags)
        const bf16x8 pa0 = *reinterpret_cast<const bf16x8*>(&P_lds[w][lq][8*lg]);
        const bf16x8 pa1 = *reinterpret_cast<const bf16x8*>(&P_lds[w][lq][32 + 8*lg]);
        #pragma unroll
        for (int dt = 0; dt < 4; ++dt) {
            const unsigned short* vp = vt_base + (size_t)(dt*16)*2048 + k0;
            bf16x8 vb0 = *reinterpret_cast<const bf16x8*>(vp);
            bf16x8 vb1 = *reinterpret_cast<const bf16x8*>(vp + 32);
            oacc[dt] = __builtin_amdgcn_mfma_f32_16x16x32_bf16(pa0, vb0, oacc[dt], 0, 0, 0);
            oacc[dt] = __builtin_amdgcn_mfma_f32_16x16x32_bf16(pa1, vb1, oacc[dt], 0, 0, 0);
        }
    }

    __syncthreads();   // all AW writes visible

    // epilogue MFMA: oacc += AW @ TvbT  (ids 1..255; col 0 is zero)
    const int awrow = w*16 + lq;                       // A row = lane%16
    #pragma unroll
    for (int kf = 0; kf < 8; ++kf) {
        const int chunk = (lg + 4*kf) ^ (lq & 7);      // (col>>3) ^ (row&7)
        const bf16x8 pa = *reinterpret_cast<const bf16x8*>(&AW[awrow][chunk << 3]);
        #pragma unroll
        for (int dt = 0; dt < 4; ++dt) {
            const bf16x8 vb = *reinterpret_cast<const bf16x8*>(
                &TvbT[(size_t)(16*dt + lq) * 256 + 32*kf + 8*lg]);
            oacc[dt] = __builtin_amdgcn_mfma_f32_16x16x32_bf16(pa, vb, oacc[dt], 0, 0, 0);
        }
    }

    // reduce l and tails over the 16 lanes sharing each row; add rank-1 tails
    const int b = bh >> 4, h = bh & 15;
    #pragma unroll
    for (int r = 0; r < 4; ++r) {
        float ls = lp[r], a0 = w0a[r], a2 = w256a[r];
        #pragma unroll
        for (int off = 1; off < 16; off <<= 1) {
            ls += __shfl_xor(ls, off);
            a0 += __shfl_xor(a0, off);
            a2 += __shfl_xor(a2, off);
        }
        const float inv = 1.f / ls;
        const int q = qrow + r;
        #pragma unroll
        for (int dt = 0; dt < 4; ++dt) {
            const float tv0 = Tv[16*dt + lq];                  // Tv[0][d]
            const float tv2 = Tv[(size_t)256*64 + 16*dt + lq]; // Tv[256][d]
            Ow[((size_t)b*S_ + q)*H_ + h*64 + 16*dt + lq] =
                (oacc[dt][r] + a0*tv0 + a2*tv2) * inv;
        }
    }
}

// ---------------------------------------------------------------------------
extern "C" void kernel_launch(void* const* d_in, const int* in_sizes, int n_in,
                              void* d_out, int out_size, void* d_ws, size_t ws_size,
                              hipStream_t stream) {
    const float* query = (const float*)d_in[0];
    const float* key_  = (const float*)d_in[1];
    const float* value = (const float*)d_in[2];
    const float* Wq = (const float*)d_in[3];
    const float* bq = (const float*)d_in[4];
    const float* Wk = (const float*)d_in[5];
    const float* bk = (const float*)d_in[6];
    const float* Wv = (const float*)d_in[7];
    const float* bv = (const float*)d_in[8];
    const float* Wo = (const float*)d_in[9];
    const float* bo = (const float*)d_in[10];
    const float* Tk = (const float*)d_in[11];
    const float* Tv = (const float*)d_in[12];

    float* ws = (float*)d_ws;
    float* Qw   = ws;                                  //  4,194,304 f
    float* relP = Qw + (size_t)4194304;                // 16,842,752 f
    float* Ow   = relP + (size_t)16842752;             //  4,194,304 f
    unsigned short* Qb = (unsigned short*)(Ow + (size_t)4194304);
    unsigned short* Kb = Qb + (size_t)4194304;
    unsigned short* Vt = Kb + (size_t)4194304;
    unsigned short* TvbT = Vt + (size_t)4194304;       //     16,384 h

    const dim3 gemmGrid(16, 64), blk(256);
    proj_gemm<0><<<gemmGrid, blk, 0, stream>>>(query, Wq, bq, Qw, Qb);
    proj_gemm<4><<<gemmGrid, blk, 0, stream>>>(key_,  Wk, bk, nullptr, Kb);
    proj_gemm<3><<<gemmGrid, blk, 0, stream>>>(value, Wv, bv, nullptr, Vt);
    tvb_prep<<<dim3(64), blk, 0, stream>>>(Tv, TvbT);
    relp_gemm<<<dim3(5, 32, 32), blk, 0, stream>>>(Qw, Tk, relP);
    flash_attn4<<<dim3(32, 32), blk, 0, stream>>>(Qb, Kb, Vt, relP, TvbT, Tv, Ow);
    proj_gemm<1><<<gemmGrid, blk, 0, stream>>>(Ow, Wo, bo, (float*)d_out, nullptr);
}

// Round 7
// 645.990 us; speedup vs baseline: 9.8916x; 1.5520x over previous
//
#include <hip/hip_runtime.h>
#include <math.h>
#include <cstddef>

// B=2, S=2048, H=1024, NUM_HEADS=16, hd=64, MAX_REL=128 -> 257 table rows
// Workspace (126.12 MB, same as prior rounds):
//   relP [32][2048][257] f32
//   Ow   [2][2048][1024] f32
//   WqT/WkT/WvT/WoT [1024 n][1024 k] bf16
//   Qb/Kb/Vb [32][2048][64] bf16 (head layout)
//   Vt  [32][64][2048] bf16 (V transposed d-major)
//   TvbT [64][256] bf16

#define S_ 2048
#define H_ 1024
#define NREL 257

typedef __attribute__((ext_vector_type(8))) short bf16x8;
typedef __attribute__((ext_vector_type(4))) float f32x4;

__device__ __forceinline__ unsigned short f2bf(float x) {
    unsigned u = __builtin_bit_cast(unsigned, x);
    return (unsigned short)((u + 0x7FFFu + ((u >> 16) & 1u)) >> 16);
}
__device__ __forceinline__ float bf2f(unsigned short u) {
    return __builtin_bit_cast(float, (unsigned)u << 16);
}

// ---------------------------------------------------------------------------
// wt_prep: W [1024 k][1024 n] f32 -> WT [1024 n][1024 k] bf16 (tiled transpose)
// ---------------------------------------------------------------------------
__global__ __launch_bounds__(256) void wt_prep(const float* __restrict__ W,
        unsigned short* __restrict__ WT) {
    __shared__ float tile[64][65];
    const int k0 = blockIdx.y * 64, n0 = blockIdx.x * 64;
    const int t = threadIdx.x;
    const int tr = t >> 4, tc = t & 15;
    #pragma unroll
    for (int it = 0; it < 4; ++it) {
        const int r = tr + 16 * it;
        const float4 w4 = *reinterpret_cast<const float4*>(
            &W[(size_t)(k0 + r) * H_ + n0 + tc * 4]);
        tile[r][tc*4+0] = w4.x; tile[r][tc*4+1] = w4.y;
        tile[r][tc*4+2] = w4.z; tile[r][tc*4+3] = w4.w;
    }
    __syncthreads();
    #pragma unroll
    for (int it = 0; it < 4; ++it) {
        const int n = tr + 16 * it;
        ushort4 o;
        o.x = f2bf(tile[tc*4+0][n]); o.y = f2bf(tile[tc*4+1][n]);
        o.z = f2bf(tile[tc*4+2][n]); o.w = f2bf(tile[tc*4+3][n]);
        *reinterpret_cast<ushort4*>(&WT[(size_t)(n0 + n) * H_ + k0 + tc * 4]) = o;
    }
}

// ---------------------------------------------------------------------------
// proj_mfma: C[4096,1024] = X(f32) @ WT^T + bias, bf16 MFMA, fp32 accum.
// MODE 0: bf16 head layout [B,16,S,64] (Q/K/V); MODE 1: f32 flat (output proj)
// 64x64 tile, BK=64, 4 waves each computing a 32x32 quadrant (2x2 MFMA frags).
// ---------------------------------------------------------------------------
template<int MODE>
__global__ __launch_bounds__(256) void proj_mfma(const float* __restrict__ X,
        const unsigned short* __restrict__ WT, const float* __restrict__ bias,
        float* __restrict__ Y, unsigned short* __restrict__ Yb) {
    __shared__ unsigned short Xs[64][72];   // [m][k]
    __shared__ unsigned short Ws[64][72];   // [n][k]
    const int m0 = blockIdx.y * 64, n0 = blockIdx.x * 64;
    const int t = threadIdx.x;
    const int w = t >> 6, l = t & 63, lq = l & 15, lg = l >> 4;
    const int mw = (w >> 1) * 32, nw = (w & 1) * 32;
    f32x4 acc[2][2];
    acc[0][0] = acc[0][1] = acc[1][0] = acc[1][1] = (f32x4){0.f, 0.f, 0.f, 0.f};
    for (int k0 = 0; k0 < H_; k0 += 64) {
        __syncthreads();
        #pragma unroll
        for (int it = 0; it < 4; ++it) {     // X tile 64x64 f32 -> bf16
            const int r = (t >> 4) + 16 * it, c = (t & 15) * 4;
            const float4 x4 = *reinterpret_cast<const float4*>(
                &X[(size_t)(m0 + r) * H_ + k0 + c]);
            ushort4 xb;
            xb.x = f2bf(x4.x); xb.y = f2bf(x4.y); xb.z = f2bf(x4.z); xb.w = f2bf(x4.w);
            *reinterpret_cast<ushort4*>(&Xs[r][c]) = xb;
        }
        #pragma unroll
        for (int it = 0; it < 2; ++it) {     // W tile 64x64 bf16
            const int idx = t + 256 * it, r = idx >> 3, c8 = idx & 7;
            *reinterpret_cast<uint4*>(&Ws[r][c8 * 8]) =
                *reinterpret_cast<const uint4*>(&WT[(size_t)(n0 + r) * H_ + k0 + c8 * 8]);
        }
        __syncthreads();
        #pragma unroll
        for (int kk = 0; kk < 2; ++kk) {
            const bf16x8 a0 = *reinterpret_cast<const bf16x8*>(&Xs[mw + lq][kk*32 + 8*lg]);
            const bf16x8 a1 = *reinterpret_cast<const bf16x8*>(&Xs[mw + 16 + lq][kk*32 + 8*lg]);
            const bf16x8 b0 = *reinterpret_cast<const bf16x8*>(&Ws[nw + lq][kk*32 + 8*lg]);
            const bf16x8 b1 = *reinterpret_cast<const bf16x8*>(&Ws[nw + 16 + lq][kk*32 + 8*lg]);
            acc[0][0] = __builtin_amdgcn_mfma_f32_16x16x32_bf16(a0, b0, acc[0][0], 0, 0, 0);
            acc[0][1] = __builtin_amdgcn_mfma_f32_16x16x32_bf16(a0, b1, acc[0][1], 0, 0, 0);
            acc[1][0] = __builtin_amdgcn_mfma_f32_16x16x32_bf16(a1, b0, acc[1][0], 0, 0, 0);
            acc[1][1] = __builtin_amdgcn_mfma_f32_16x16x32_bf16(a1, b1, acc[1][1], 0, 0, 0);
        }
    }
    #pragma unroll
    for (int i = 0; i < 2; ++i) {
        #pragma unroll
        for (int r = 0; r < 4; ++r) {
            const int m = m0 + mw + 16*i + 4*lg + r;
            #pragma unroll
            for (int j = 0; j < 2; ++j) {
                const int n = n0 + nw + 16*j + lq;
                const float val = acc[i][j][r] + bias[n];
                if (MODE == 1) {
                    Y[(size_t)m * H_ + n] = val;
                } else {
                    const int b = m >> 11, s = m & 2047, h = n >> 6, d = n & 63;
                    Yb[(((size_t)b*16 + h) * S_ + s) * 64 + d] = f2bf(val);
                }
            }
        }
    }
}

// ---------------------------------------------------------------------------
// vtrans: Vb [bh][2048 s][64 d] bf16 -> Vt [bh][64 d][2048 s] bf16
// ---------------------------------------------------------------------------
__global__ __launch_bounds__(256) void vtrans(const unsigned short* __restrict__ Vb,
        unsigned short* __restrict__ Vt) {
    __shared__ unsigned short tile[64][72];   // [s][d]
    const int bh = blockIdx.y;
    const int s0 = blockIdx.x * 64;
    const int t = threadIdx.x;
    #pragma unroll
    for (int it = 0; it < 2; ++it) {
        const int idx = t + 256 * it, r = idx >> 3, c8 = idx & 7;
        *reinterpret_cast<uint4*>(&tile[r][c8 * 8]) =
            *reinterpret_cast<const uint4*>(
                &Vb[((size_t)bh * S_ + s0 + r) * 64 + c8 * 8]);
    }
    __syncthreads();
    #pragma unroll
    for (int it = 0; it < 2; ++it) {
        const int idx = t + 256 * it, d = idx >> 3, sc8 = idx & 7;
        ushort4 o0, o1;
        o0.x = tile[sc8*8+0][d]; o0.y = tile[sc8*8+1][d];
        o0.z = tile[sc8*8+2][d]; o0.w = tile[sc8*8+3][d];
        o1.x = tile[sc8*8+4][d]; o1.y = tile[sc8*8+5][d];
        o1.z = tile[sc8*8+6][d]; o1.w = tile[sc8*8+7][d];
        unsigned short* dst = &Vt[((size_t)bh*64 + d) * S_ + s0 + sc8*8];
        *reinterpret_cast<ushort4*>(dst)     = o0;
        *reinterpret_cast<ushort4*>(dst + 4) = o1;
    }
}

// ---------------------------------------------------------------------------
// relp_gemm: relP[bh][s][i] = sum_d Qb[bh][s][d] * Tk[i][d]  (fp32 accum)
// ---------------------------------------------------------------------------
__global__ __launch_bounds__(256) void relp_gemm(const unsigned short* __restrict__ Qb,
        const float* __restrict__ Tk, float* __restrict__ relPg) {
    __shared__ float As[64][68];   // [d][srow]
    __shared__ float Bs[64][68];   // [d][i]
    const int bh = blockIdx.z;
    const int s0 = blockIdx.y * 64;
    const int i0 = blockIdx.x * 64;
    const int t = threadIdx.x;
    const int tx = t & 15, ty = t >> 4;
    #pragma unroll
    for (int j = 0; j < 4; ++j) {
        int f = t + j * 256;
        int row = f >> 4, db = f & 15;
        ushort4 q4 = *reinterpret_cast<const ushort4*>(
            &Qb[((size_t)bh * S_ + s0 + row) * 64 + db * 4]);
        As[db*4+0][row] = bf2f(q4.x); As[db*4+1][row] = bf2f(q4.y);
        As[db*4+2][row] = bf2f(q4.z); As[db*4+3][row] = bf2f(q4.w);
        int i = i0 + row;
        float4 t4 = make_float4(0.f, 0.f, 0.f, 0.f);
        if (i < NREL)
            t4 = *reinterpret_cast<const float4*>(&Tk[(size_t)i * 64 + db * 4]);
        Bs[db*4+0][row] = t4.x; Bs[db*4+1][row] = t4.y;
        Bs[db*4+2][row] = t4.z; Bs[db*4+3][row] = t4.w;
    }
    __syncthreads();
    float acc[4][4] = {};
    #pragma unroll 8
    for (int d = 0; d < 64; ++d) {
        float a[4], b[4];
        *reinterpret_cast<float4*>(a) = *reinterpret_cast<float4*>(&As[d][ty*4]);
        *reinterpret_cast<float4*>(b) = *reinterpret_cast<float4*>(&Bs[d][tx*4]);
        #pragma unroll
        for (int i = 0; i < 4; ++i)
            #pragma unroll
            for (int j = 0; j < 4; ++j)
                acc[i][j] += a[i] * b[j];
    }
    #pragma unroll
    for (int i = 0; i < 4; ++i) {
        const int srow = s0 + ty*4 + i;
        #pragma unroll
        for (int j = 0; j < 4; ++j) {
            const int ic = i0 + tx*4 + j;
            if (ic < NREL)
                relPg[((size_t)bh * S_ + srow) * NREL + ic] = acc[i][j];
        }
    }
}

// ---------------------------------------------------------------------------
// TvbT[d][id] = bf16(Tv[id][d]) for id in [0,256)
// ---------------------------------------------------------------------------
__global__ __launch_bounds__(256) void tvb_prep(const float* __restrict__ Tv,
        unsigned short* __restrict__ TvbT) {
    const int idx = blockIdx.x * 256 + threadIdx.x;   // 16384 total
    const int d = idx >> 8, id = idx & 255;
    TvbT[idx] = f2bf(Tv[(size_t)id * 64 + d]);
}

// ---------------------------------------------------------------------------
// flash_attn5: barrier-FREE bf16 MFMA flash attention + fused rel_v.
// All LDS (P_lds, AW) is per-wave private -> __syncthreads replaced by
// wave-local s_waitcnt lgkmcnt(0) + sched_barrier(0) (rule: hipcc can hoist
// past inline-asm waits). K is register double-buffered (dist-1 prefetch);
// V loaded at body top (used ~500cyc later). Waves slip freely -> global
// latency hidden by cross-wave overlap instead of lockstep stalls.
// ---------------------------------------------------------------------------
__global__ __launch_bounds__(256) void flash_attn5(
        const unsigned short* __restrict__ Qb, const unsigned short* __restrict__ Kb,
        const unsigned short* __restrict__ Vt, const float* __restrict__ relP,
        const unsigned short* __restrict__ TvbT, const float* __restrict__ Tv,
        float* __restrict__ Ow) {
    __shared__ __align__(16) unsigned short AW[64][256];        // 32 KB, per-wave rows
    __shared__ __align__(16) unsigned short P_lds[4][16][72];   // 9 KB, per-wave slice

    const int t = threadIdx.x;
    const int w = t >> 6, l = t & 63;
    const int lq = l & 15, lg = l >> 4;
    const int bh = blockIdx.y;
    const int r0 = blockIdx.x * 64;
    const size_t bhS = (size_t)bh * S_;

    {   // per-wave AW zero (own 16 rows)
        uint4* awz = reinterpret_cast<uint4*>(&AW[w*16][0]);
        #pragma unroll
        for (int i = 0; i < 8; ++i) awz[l + 64*i] = make_uint4(0,0,0,0);
    }
    asm volatile("s_waitcnt lgkmcnt(0)" ::: "memory");

    const unsigned short* qp = Qb + (bhS + r0 + w*16 + lq) * 64 + 8*lg;
    const bf16x8 qa0 = *reinterpret_cast<const bf16x8*>(qp);
    const bf16x8 qa1 = *reinterpret_cast<const bf16x8*>(qp + 32);

    const int qrow = r0 + w*16 + 4*lg;
    size_t awb[4];
    float b0[4], b256[4];
    #pragma unroll
    for (int r = 0; r < 4; ++r) {
        awb[r] = (bhS + qrow + r) * NREL;
        b0[r]   = relP[awb[r] + 0];
        b256[r] = relP[awb[r] + 256];
    }

    f32x4 oacc[4];
    #pragma unroll
    for (int dt = 0; dt < 4; ++dt) oacc[dt] = (f32x4){0.f, 0.f, 0.f, 0.f};
    float lp[4]    = {0.f, 0.f, 0.f, 0.f};
    float w0a[4]   = {0.f, 0.f, 0.f, 0.f};
    float w256a[4] = {0.f, 0.f, 0.f, 0.f};

    const unsigned short* kb_base = Kb + (bhS + lq) * 64 + 8*lg;
    const unsigned short* vt_base = Vt + ((size_t)bh*64 + lq) * 2048 + 8*lg;

    bf16x8 kA0[4], kA1[4], kB0[4], kB1[4];
    #pragma unroll
    for (int kt = 0; kt < 4; ++kt) {
        const unsigned short* kp = kb_base + (size_t)(kt*16) * 64;
        kA0[kt] = *reinterpret_cast<const bf16x8*>(kp);
        kA1[kt] = *reinterpret_cast<const bf16x8*>(kp + 32);
    }

#define FLASH_BODY(K0C, KC0, KC1, KN0, KN1)                                          \
    {                                                                                \
        const int k0 = (K0C);                                                        \
        bf16x8 vf0[4], vf1[4];                                                       \
        _Pragma("unroll")                                                            \
        for (int dt = 0; dt < 4; ++dt) {                                             \
            const unsigned short* vp = vt_base + (size_t)(dt*16)*2048 + k0;          \
            vf0[dt] = *reinterpret_cast<const bf16x8*>(vp);                          \
            vf1[dt] = *reinterpret_cast<const bf16x8*>(vp + 32);                     \
        }                                                                            \
        f32x4 sacc[4];                                                               \
        _Pragma("unroll")                                                            \
        for (int kt = 0; kt < 4; ++kt) {                                             \
            f32x4 s_ = (f32x4){0.f, 0.f, 0.f, 0.f};                                  \
            s_ = __builtin_amdgcn_mfma_f32_16x16x32_bf16(qa0, KC0[kt], s_, 0, 0, 0); \
            s_ = __builtin_amdgcn_mfma_f32_16x16x32_bf16(qa1, KC1[kt], s_, 0, 0, 0); \
            sacc[kt] = s_;                                                           \
        }                                                                            \
        if (k0 + 64 < S_) {                                                          \
            _Pragma("unroll")                                                        \
            for (int kt = 0; kt < 4; ++kt) {                                         \
                const unsigned short* kp = kb_base + (size_t)(k0 + 64 + kt*16)*64;   \
                KN0[kt] = *reinterpret_cast<const bf16x8*>(kp);                      \
                KN1[kt] = *reinterpret_cast<const bf16x8*>(kp + 32);                 \
            }                                                                        \
        }                                                                            \
        const int d0 = k0 - r0;                                                      \
        if (d0 <= -192) {                                                            \
            _Pragma("unroll")                                                        \
            for (int kt = 0; kt < 4; ++kt)                                           \
                _Pragma("unroll")                                                    \
                for (int r = 0; r < 4; ++r) {                                        \
                    const float pe = __expf((sacc[kt][r] + b256[r]) * 0.125f);       \
                    lp[r] += pe; w256a[r] += pe;                                     \
                    P_lds[w][4*lg + r][kt*16 + lq] = f2bf(pe);                       \
                }                                                                    \
        } else if (d0 >= 192) {                                                      \
            _Pragma("unroll")                                                        \
            for (int kt = 0; kt < 4; ++kt)                                           \
                _Pragma("unroll")                                                    \
                for (int r = 0; r < 4; ++r) {                                        \
                    const float pe = __expf((sacc[kt][r] + b0[r]) * 0.125f);         \
                    lp[r] += pe; w0a[r] += pe;                                       \
                    P_lds[w][4*lg + r][kt*16 + lq] = f2bf(pe);                       \
                }                                                                    \
        } else {                                                                     \
            _Pragma("unroll")                                                        \
            for (int kt = 0; kt < 4; ++kt) {                                         \
                const int kg = k0 + kt*16 + lq;                                      \
                _Pragma("unroll")                                                    \
                for (int r = 0; r < 4; ++r) {                                        \
                    int rel = (qrow + r) - kg;                                       \
                    rel = rel > 128 ? 128 : (rel < -128 ? -128 : rel);               \
                    const int id = rel + 128;                                        \
                    const bool mid = (unsigned)(id - 1) < 255u;                      \
                    const float bias_ = mid ? relP[awb[r] + id]                      \
                                            : (id == 0 ? b0[r] : b256[r]);           \
                    const float pe = __expf((sacc[kt][r] + bias_) * 0.125f);         \
                    lp[r] += pe;                                                     \
                    if (id == 0) w0a[r] += pe;                                       \
                    else if (id == 256) w256a[r] += pe;                              \
                    else {                                                           \
                        const int row = w*16 + 4*lg + r;                             \
                        AW[row][((((unsigned)id >> 3) ^ (row & 7u)) << 3) + (id & 7)]\
                            = f2bf(pe);                                              \
                    }                                                                \
                    P_lds[w][4*lg + r][kt*16 + lq] = f2bf(pe);                       \
                }                                                                    \
            }                                                                        \
        }                                                                            \
        asm volatile("s_waitcnt lgkmcnt(0)" ::: "memory");                           \
        __builtin_amdgcn_sched_barrier(0);                                           \
        const bf16x8 pa0 = *reinterpret_cast<const bf16x8*>(&P_lds[w][lq][8*lg]);    \
        const bf16x8 pa1 = *reinterpret_cast<const bf16x8*>(&P_lds[w][lq][32+8*lg]); \
        _Pragma("unroll")                                                            \
        for (int dt = 0; dt < 4; ++dt) {                                             \
            oacc[dt] = __builtin_amdgcn_mfma_f32_16x16x32_bf16(pa0, vf0[dt], oacc[dt], 0, 0, 0); \
            oacc[dt] = __builtin_amdgcn_mfma_f32_16x16x32_bf16(pa1, vf1[dt], oacc[dt], 0, 0, 0); \
        }                                                                            \
    }

    for (int k0i = 0; k0i < S_; k0i += 128) {
        FLASH_BODY(k0i,      kA0, kA1, kB0, kB1);
        FLASH_BODY(k0i + 64, kB0, kB1, kA0, kA1);
    }
#undef FLASH_BODY

    asm volatile("s_waitcnt lgkmcnt(0)" ::: "memory");
    __builtin_amdgcn_sched_barrier(0);

    // epilogue MFMA: oacc += AW @ TvbT  (ids 1..255; col 0 is zero)
    const int awrow = w*16 + lq;
    #pragma unroll
    for (int kf = 0; kf < 8; ++kf) {
        const int chunk = (lg + 4*kf) ^ (lq & 7);
        const bf16x8 pa = *reinterpret_cast<const bf16x8*>(&AW[awrow][chunk << 3]);
        #pragma unroll
        for (int dt = 0; dt < 4; ++dt) {
            const bf16x8 vb = *reinterpret_cast<const bf16x8*>(
                &TvbT[(size_t)(16*dt + lq) * 256 + 32*kf + 8*lg]);
            oacc[dt] = __builtin_amdgcn_mfma_f32_16x16x32_bf16(pa, vb, oacc[dt], 0, 0, 0);
        }
    }

    const int b = bh >> 4, h = bh & 15;
    #pragma unroll
    for (int r = 0; r < 4; ++r) {
        float ls = lp[r], a0 = w0a[r], a2 = w256a[r];
        #pragma unroll
        for (int off = 1; off < 16; off <<= 1) {
            ls += __shfl_xor(ls, off);
            a0 += __shfl_xor(a0, off);
            a2 += __shfl_xor(a2, off);
        }
        const float inv = 1.f / ls;
        const int q = qrow + r;
        #pragma unroll
        for (int dt = 0; dt < 4; ++dt) {
            const float tv0 = Tv[16*dt + lq];
            const float tv2 = Tv[(size_t)256*64 + 16*dt + lq];
            Ow[((size_t)b*S_ + q)*H_ + h*64 + 16*dt + lq] =
                (oacc[dt][r] + a0*tv0 + a2*tv2) * inv;
        }
    }
}

// ---------------------------------------------------------------------------
extern "C" void kernel_launch(void* const* d_in, const int* in_sizes, int n_in,
                              void* d_out, int out_size, void* d_ws, size_t ws_size,
                              hipStream_t stream) {
    const float* query = (const float*)d_in[0];
    const float* key_  = (const float*)d_in[1];
    const float* value = (const float*)d_in[2];
    const float* Wq = (const float*)d_in[3];
    const float* bq = (const float*)d_in[4];
    const float* Wk = (const float*)d_in[5];
    const float* bk = (const float*)d_in[6];
    const float* Wv = (const float*)d_in[7];
    const float* bv = (const float*)d_in[8];
    const float* Wo = (const float*)d_in[9];
    const float* bo = (const float*)d_in[10];
    const float* Tk = (const float*)d_in[11];
    const float* Tv = (const float*)d_in[12];

    float* ws = (float*)d_ws;
    float* relP = ws;                                   // 16,842,752 f
    float* Ow   = relP + (size_t)16842752;              //  4,194,304 f
    unsigned short* WqT = (unsigned short*)(Ow + (size_t)4194304);
    unsigned short* WkT = WqT + (size_t)1048576;
    unsigned short* WvT = WkT + (size_t)1048576;
    unsigned short* WoT = WvT + (size_t)1048576;
    unsigned short* Qb  = WoT + (size_t)1048576;
    unsigned short* Kb  = Qb  + (size_t)4194304;
    unsigned short* Vb  = Kb  + (size_t)4194304;
    unsigned short* Vt  = Vb  + (size_t)4194304;
    unsigned short* TvbT = Vt + (size_t)4194304;        // 16,384 h

    const dim3 blk(256);
    const dim3 wtGrid(16, 16), pGrid(16, 64);
    wt_prep<<<wtGrid, blk, 0, stream>>>(Wq, WqT);
    wt_prep<<<wtGrid, blk, 0, stream>>>(Wk, WkT);
    wt_prep<<<wtGrid, blk, 0, stream>>>(Wv, WvT);
    wt_prep<<<wtGrid, blk, 0, stream>>>(Wo, WoT);
    proj_mfma<0><<<pGrid, blk, 0, stream>>>(query, WqT, bq, nullptr, Qb);
    proj_mfma<0><<<pGrid, blk, 0, stream>>>(key_,  WkT, bk, nullptr, Kb);
    proj_mfma<0><<<pGrid, blk, 0, stream>>>(value, WvT, bv, nullptr, Vb);
    vtrans<<<dim3(32, 32), blk, 0, stream>>>(Vb, Vt);
    tvb_prep<<<dim3(64), blk, 0, stream>>>(Tv, TvbT);
    relp_gemm<<<dim3(5, 32, 32), blk, 0, stream>>>(Qb, Tk, relP);
    flash_attn5<<<dim3(32, 32), blk, 0, stream>>>(Qb, Kb, Vt, relP, TvbT, Tv, Ow);
    proj_mfma<1><<<pGrid, blk, 0, stream>>>(Ow, WoT, bo, (float*)d_out, nullptr);
}